// Round 2
// baseline (40.326 us; speedup 1.0000x reference)
//
#include <hip/hip_runtime.h>
#include <math.h>

// Graph2GraphModel fused single-kernel version.
// lidar-chain GCN (3 layers, HID=64, halo-split over 24 blocks)
// -> masked mean pool -> Wp(64x512) -> relu(Wm1 512x1024) -> Wm2(1024x200).
// Two grid-wide spin barriers (device-scope atomics) replace kernel splits.
// Barrier words are zeroed each call by an 8-byte hipMemsetAsync node.

#define NSCAN 360
#define HID 64
#define NB 24       // blocks
#define CHUNK 15    // nodes per block (24*15 = 360)
#define EXT 21      // CHUNK + 6 halo

// ws float-offset layout
#define WSF_PARTIAL 16                  // NB*HID floats
#define WSF_M1      (16 + NB * HID)     // 1024 floats

__device__ __forceinline__ void grid_bar(int* bar) {
  __syncthreads();
  __threadfence();                      // publish this block's writes (agent scope)
  if (threadIdx.x == 0) {
    int gen = __hip_atomic_load(&bar[1], __ATOMIC_RELAXED, __HIP_MEMORY_SCOPE_AGENT);
    int old = __hip_atomic_fetch_add(&bar[0], 1, __ATOMIC_ACQ_REL, __HIP_MEMORY_SCOPE_AGENT);
    if (old == NB - 1) {
      __hip_atomic_store(&bar[0], 0, __ATOMIC_RELAXED, __HIP_MEMORY_SCOPE_AGENT);
      __hip_atomic_store(&bar[1], gen + 1, __ATOMIC_RELEASE, __HIP_MEMORY_SCOPE_AGENT);
    } else {
      while (__hip_atomic_load(&bar[1], __ATOMIC_ACQUIRE, __HIP_MEMORY_SCOPE_AGENT) == gen)
        __builtin_amdgcn_s_sleep(1);
    }
  }
  __syncthreads();
  __threadfence();                      // invalidate stale caches before reads
}

__device__ __forceinline__ void loadW64(int t, const float* __restrict__ W,
                                        float (*sW)[HID]) {
  const float4* src = reinterpret_cast<const float4*>(W);
  float4* dst = reinterpret_cast<float4*>(&sW[0][0]);
  for (int i = t; i < 1024; i += 256) dst[i] = src[i];
}

__device__ __forceinline__ void matmul64(int t, int glo, int ghi, int base,
                                         const float (*sh)[HID],
                                         float (*shw)[HID],
                                         const float (*sW)[HID]) {
  const int cnt = ghi - glo;
  const int off = glo - base;
  for (int g4 = t; g4 < cnt * 16; g4 += 256) {
    const int nl = off + (g4 >> 4);
    const int j4 = (g4 & 15) << 2;
    float a0 = 0.f, a1 = 0.f, a2 = 0.f, a3 = 0.f;
#pragma unroll 16
    for (int k = 0; k < HID; ++k) {
      const float hv = sh[nl][k];
      const float4 w = *reinterpret_cast<const float4*>(&sW[k][j4]);
      a0 = fmaf(hv, w.x, a0);
      a1 = fmaf(hv, w.y, a1);
      a2 = fmaf(hv, w.z, a2);
      a3 = fmaf(hv, w.w, a3);
    }
    float4 r; r.x = a0; r.y = a1; r.z = a2; r.w = a3;
    *reinterpret_cast<float4*>(&shw[nl][j4]) = r;
  }
}

__device__ __forceinline__ void agg_relu(int t, int olo, int ohi, int base,
                                         const float (*shw)[HID],
                                         float (*sh)[HID],
                                         const float* sinv,
                                         const float* scoef,
                                         const float* __restrict__ bias) {
  const int cnt = ohi - olo;
  for (int o = t; o < cnt * HID; o += 256) {
    const int nl = o >> 6, j = o & 63;
    const int n = olo + nl;
    float v = sinv[n] * sinv[n] * shw[n - base][j];
    if (n > 0)         v += scoef[n - 1] * shw[n - 1 - base][j];
    if (n < NSCAN - 1) v += scoef[n]     * shw[n + 1 - base][j];
    v += bias[j];
    sh[n - base][j] = fmaxf(v, 0.f);
  }
}

__global__ __launch_bounds__(256) void fused_g2g(
    const float* __restrict__ x,
    const float* __restrict__ W1, const float* __restrict__ b1,
    const float* __restrict__ W2, const float* __restrict__ b2,
    const float* __restrict__ W3, const float* __restrict__ b3,
    const float* __restrict__ Wp, const float* __restrict__ bp,
    const float* __restrict__ Wm1, const float* __restrict__ bm1,
    const float* __restrict__ Wm2, const float* __restrict__ bm2,
    float* __restrict__ ws, float* __restrict__ out) {
  __shared__ float smask[NSCAN], sinv[NSCAN];
  __shared__ float spair[NSCAN - 1], scoef[NSCAN - 1];
  __shared__ float snod[EXT][2];
  __shared__ float sh[EXT][HID];
  __shared__ float shw[EXT][HID];
  __shared__ float sW[HID][HID];
  __shared__ float sred[4][HID];
  __shared__ float sgemb[HID];
  __shared__ float sc[512];
  __shared__ float sm1[1024];
  __shared__ float snva[4];
  __shared__ float snv;

  const int t = threadIdx.x;
  const int b = blockIdx.x;
  int* bar = (int*)ws;
  float* partial = ws + WSF_PARTIAL;
  float* m1 = ws + WSF_M1;

  const int s = b * CHUNK, e = s + CHUNK;
  const int lo3 = max(0, s - 3), hi3 = min(NSCAN, e + 3);
  const int lo2 = max(0, s - 2), hi2 = min(NSCAN, e + 2);
  const int lo1 = max(0, s - 1), hi1 = min(NSCAN, e + 1);
  const int base = lo3;

  // ---- pass1: full mask + local-halo nodes (trig only on EXT range) ----
  for (int i = t; i < NSCAN; i += 256) smask[i] = (x[i] != 1.0f) ? 1.f : 0.f;
  for (int i = lo3 + t; i < hi3; i += 256) {
    const float l = x[i];
    const double a = (double)i * (6.283185307179586476925287 / 359.0);
    snod[i - base][0] = l * (float)cos(a);
    snod[i - base][1] = l * (float)sin(a);
  }
  __syncthreads();
  // ---- pass2: pair + n_valid ----
  for (int i = t; i < NSCAN - 1; i += 256) spair[i] = smask[i] * smask[i + 1];
  {
    float mv = 0.f;
    for (int i = t; i < NSCAN; i += 256) mv += smask[i];
    for (int off = 32; off; off >>= 1) mv += __shfl_down(mv, off, 64);
    if ((t & 63) == 0) snva[t >> 6] = mv;
  }
  __syncthreads();
  // ---- pass3: inv ----
  for (int i = t; i < NSCAN; i += 256) {
    float deg = smask[i];
    if (i > 0)         deg += spair[i - 1];
    if (i < NSCAN - 1) deg += spair[i];
    sinv[i] = (deg > 0.f) ? 1.0f / sqrtf(deg) : 0.f;
  }
  if (t == 0) snv = snva[0] + snva[1] + snva[2] + snva[3];
  __syncthreads();
  // ---- pass4: coef ----
  for (int i = t; i < NSCAN - 1; i += 256)
    scoef[i] = spair[i] * sinv[i] * sinv[i + 1];
  __syncthreads();

  // ---- layer 1 (stage W2 concurrently) ----
  loadW64(t, W2, sW);
  for (int o = t; o < (hi3 - lo3) * HID; o += 256) {
    const int nl = o >> 6, j = o & 63;
    shw[nl][j] = fmaf(snod[nl][0], W1[j], snod[nl][1] * W1[HID + j]);
  }
  __syncthreads();
  agg_relu(t, lo2, hi2, base, shw, sh, sinv, scoef, b1);
  __syncthreads();
  // ---- layer 2 ----
  matmul64(t, lo2, hi2, base, sh, shw, sW);
  __syncthreads();
  agg_relu(t, lo1, hi1, base, shw, sh, sinv, scoef, b2);
  loadW64(t, W3, sW);
  __syncthreads();
  // ---- layer 3 ----
  matmul64(t, lo1, hi1, base, sh, shw, sW);
  __syncthreads();
  agg_relu(t, s, e, base, shw, sh, sinv, scoef, b3);
  __syncthreads();
  // ---- partial masked pool ----
  {
    const int jl = t & 63, g = t >> 6;
    float acc = 0.f;
    for (int n = s + g; n < e; n += 4) acc += sh[n - base][jl] * smask[n];
    sred[g][jl] = acc;
  }
  __syncthreads();
  if (t < HID)
    partial[b * HID + t] = sred[0][t] + sred[1][t] + sred[2][t] + sred[3][t];

  grid_bar(bar);

  // ---- phase B: gemb + full c (redundant per block; removes a barrier) ----
  if (t < HID) {
    float sum = 0.f;
#pragma unroll
    for (int bb = 0; bb < NB; ++bb) sum += partial[bb * HID + t];
    sgemb[t] = sum / snv;
  }
  __syncthreads();
  for (int j = t; j < 512; j += 256) {
    float acc = bp[j];
#pragma unroll 16
    for (int k = 0; k < HID; ++k) acc = fmaf(sgemb[k], Wp[k * 512 + j], acc);
    sc[j] = acc;
  }
  __syncthreads();

  // ---- phase C: m1 slice (1024 cols over 24 blocks) ----
  {
    const int J0 = (b * 1024) / NB, J1 = ((b + 1) * 1024) / NB;
    const int cnt = J1 - J0;
    const int jl = t & 63, g = t >> 6;
    float acc = 0.f;
    if (jl < cnt) {
      const float* wcol = Wm1 + J0 + jl;
      const int k0 = g * 128;
#pragma unroll 8
      for (int ki = 0; ki < 128; ++ki)
        acc = fmaf(sc[k0 + ki], wcol[(k0 + ki) * 1024], acc);
    }
    sred[g][jl] = acc;
    __syncthreads();
    if (t < cnt) {
      const float v = sred[0][t] + sred[1][t] + sred[2][t] + sred[3][t] + bm1[J0 + t];
      m1[J0 + t] = fmaxf(v, 0.f);
    }
  }

  grid_bar(bar);

  // ---- phase D: out (200 cols, 8-9 per block) ----
  for (int i = t; i < 1024; i += 256) sm1[i] = m1[i];
  __syncthreads();
  {
    const int j0  = (b < 8) ? b * 9 : 72 + (b - 8) * 8;
    const int cnt = (b < 8) ? 9 : 8;
    for (int jb = j0; jb < j0 + cnt; jb += 8) {
      const int bc = min(8, j0 + cnt - jb);
      const int jj = t & 7, kk = t >> 3;     // 8 cols x 32 k-groups
      float p = 0.f;
      if (jj < bc) {
        const float* wcol = Wm2 + jb + jj;
        const int k0 = kk * 32;
#pragma unroll 8
        for (int ki = 0; ki < 32; ++ki)
          p = fmaf(sm1[k0 + ki], wcol[(k0 + ki) * 200], p);
      }
      sc[t] = p;                             // reuse sc as [256] scratch
      __syncthreads();
      if (t < bc) {
        float sacc = bm2[jb + t];
#pragma unroll
        for (int k2 = 0; k2 < 32; ++k2) sacc += sc[k2 * 8 + t];
        out[jb + t] = sacc;
      }
      __syncthreads();
    }
  }
}

extern "C" void kernel_launch(void* const* d_in, const int* in_sizes, int n_in,
                              void* d_out, int out_size, void* d_ws,
                              size_t ws_size, hipStream_t stream) {
  const float* x   = (const float*)d_in[0];
  const float* W1  = (const float*)d_in[1];
  const float* b1  = (const float*)d_in[2];
  const float* W2  = (const float*)d_in[3];
  const float* b2  = (const float*)d_in[4];
  const float* W3  = (const float*)d_in[5];
  const float* b3  = (const float*)d_in[6];
  const float* Wp  = (const float*)d_in[7];
  const float* bp  = (const float*)d_in[8];
  const float* Wm1 = (const float*)d_in[9];
  const float* bm1 = (const float*)d_in[10];
  const float* Wm2 = (const float*)d_in[11];
  const float* bm2 = (const float*)d_in[12];

  // zero the two barrier words each call (handles 0xAA poison + undefined init)
  (void)hipMemsetAsync(d_ws, 0, 8, stream);

  fused_g2g<<<NB, 256, 0, stream>>>(x, W1, b1, W2, b2, W3, b3, Wp, bp,
                                    Wm1, bm1, Wm2, bm2,
                                    (float*)d_ws, (float*)d_out);
}

// Round 3
// 22.545 us; speedup vs baseline: 1.7887x; 1.7887x over previous
//
#include <hip/hip_runtime.h>
#include <math.h>

// Graph2GraphModel: lidar-chain GCN (3 layers, HID=64) -> masked mean pool
// -> Wp(64x512) -> relu(Wm1 512x1024) -> Wm2(1024x200).
// 3 kernels, no grid barriers (round-2 lesson: spin barriers + memset node
// cost ~15us on MI355X; kernel boundaries are cheaper).
// k1: 60 blocks x 6 nodes (+3 halo each side) -> partial pool sums
// k2: 16 blocks: gemb + c (redundant) + 64-col slice of m1
// k3: 200 blocks: one output column each

#define NSCAN 360
#define HID 64
#define NB1 60      // k1 blocks
#define CHUNK 6     // nodes per k1 block (60*6 = 360)
#define EXT 12      // CHUNK + 6 halo

// ws float-offset layout
#define WSF_PARTIAL 0                    // NB1*HID floats
#define WSF_M1      (NB1 * HID)          // 1024 floats

__device__ __forceinline__ void loadW64(int t, const float* __restrict__ W,
                                        float (*sW)[HID]) {
  const float4* src = reinterpret_cast<const float4*>(W);
  float4* dst = reinterpret_cast<float4*>(&sW[0][0]);
  for (int i = t; i < 1024; i += 256) dst[i] = src[i];
}

__device__ __forceinline__ void matmul64(int t, int glo, int ghi, int base,
                                         const float (*sh)[HID],
                                         float (*shw)[HID],
                                         const float (*sW)[HID]) {
  const int cnt = ghi - glo;
  const int off = glo - base;
  for (int g4 = t; g4 < cnt * 16; g4 += 256) {
    const int nl = off + (g4 >> 4);
    const int j4 = (g4 & 15) << 2;
    float a0 = 0.f, a1 = 0.f, a2 = 0.f, a3 = 0.f;
#pragma unroll 16
    for (int k = 0; k < HID; ++k) {
      const float hv = sh[nl][k];                     // wave broadcast
      const float4 w = *reinterpret_cast<const float4*>(&sW[k][j4]);
      a0 = fmaf(hv, w.x, a0);
      a1 = fmaf(hv, w.y, a1);
      a2 = fmaf(hv, w.z, a2);
      a3 = fmaf(hv, w.w, a3);
    }
    float4 r; r.x = a0; r.y = a1; r.z = a2; r.w = a3;
    *reinterpret_cast<float4*>(&shw[nl][j4]) = r;
  }
}

__device__ __forceinline__ void agg_relu(int t, int olo, int ohi, int base,
                                         const float (*shw)[HID],
                                         float (*sh)[HID],
                                         const float* sinv,
                                         const float* scoef,
                                         const float* __restrict__ bias) {
  const int cnt = ohi - olo;
  for (int o = t; o < cnt * HID; o += 256) {
    const int nl = o >> 6, j = o & 63;
    const int n = olo + nl;
    float v = sinv[n] * sinv[n] * shw[n - base][j];
    if (n > 0)         v += scoef[n - 1] * shw[n - 1 - base][j];
    if (n < NSCAN - 1) v += scoef[n]     * shw[n + 1 - base][j];
    v += bias[j];
    sh[n - base][j] = fmaxf(v, 0.f);
  }
}

__global__ __launch_bounds__(256) void k1_gcn(
    const float* __restrict__ x,
    const float* __restrict__ W1, const float* __restrict__ b1,
    const float* __restrict__ W2, const float* __restrict__ b2,
    const float* __restrict__ W3, const float* __restrict__ b3,
    float* __restrict__ partial) {
  __shared__ float smask[NSCAN];
  __shared__ float sinv[NSCAN];
  __shared__ float scoef[NSCAN - 1];
  __shared__ float snod[EXT][2];
  __shared__ float sh[EXT][HID];
  __shared__ float shw[EXT][HID];
  __shared__ float sW[HID][HID];
  __shared__ float sred[4][HID];

  const int t = threadIdx.x;
  const int b = blockIdx.x;

  const int s = b * CHUNK, e = s + CHUNK;
  const int lo3 = max(0, s - 3), hi3 = min(NSCAN, e + 3);
  const int lo2 = max(0, s - 2), hi2 = min(NSCAN, e + 2);
  const int lo1 = max(0, s - 1), hi1 = min(NSCAN, e + 1);
  const int base = lo3;

  // ---- mask (full range) + local halo nodes (trig on <=12 nodes) ----
  for (int i = t; i < NSCAN; i += 256) smask[i] = (x[i] != 1.0f) ? 1.f : 0.f;
  for (int i = lo3 + t; i < hi3; i += 256) {
    const float l = x[i];
    const double a = (double)i * (6.283185307179586476925287 / 359.0);
    snod[i - base][0] = l * (float)cos(a);
    snod[i - base][1] = l * (float)sin(a);
  }
  __syncthreads();
  // deg/inv (pair folded in: deg = m[i]*(1 + m[i-1] + m[i+1]))
  for (int i = t; i < NSCAN; i += 256) {
    const float m = smask[i];
    float deg = m;
    if (i > 0)         deg += m * smask[i - 1];
    if (i < NSCAN - 1) deg += m * smask[i + 1];
    sinv[i] = (deg > 0.f) ? 1.0f / sqrtf(deg) : 0.f;
  }
  __syncthreads();
  for (int i = t; i < NSCAN - 1; i += 256)
    scoef[i] = smask[i] * smask[i + 1] * sinv[i] * sinv[i + 1];
  __syncthreads();

  // ---- layer 1 (stage W2 concurrently) ----
  loadW64(t, W2, sW);
  for (int o = t; o < (hi3 - lo3) * HID; o += 256) {
    const int nl = o >> 6, j = o & 63;
    shw[nl][j] = fmaf(snod[nl][0], W1[j], snod[nl][1] * W1[HID + j]);
  }
  __syncthreads();
  agg_relu(t, lo2, hi2, base, shw, sh, sinv, scoef, b1);
  __syncthreads();
  // ---- layer 2 ----
  matmul64(t, lo2, hi2, base, sh, shw, sW);
  __syncthreads();
  agg_relu(t, lo1, hi1, base, shw, sh, sinv, scoef, b2);
  loadW64(t, W3, sW);
  __syncthreads();
  // ---- layer 3 ----
  matmul64(t, lo1, hi1, base, sh, shw, sW);
  __syncthreads();
  agg_relu(t, s, e, base, shw, sh, sinv, scoef, b3);
  __syncthreads();
  // ---- partial masked pool over own chunk ----
  {
    const int jl = t & 63, g = t >> 6;
    float acc = 0.f;
    for (int n = s + g; n < e; n += 4) acc += sh[n - base][jl] * smask[n];
    sred[g][jl] = acc;
  }
  __syncthreads();
  if (t < HID)
    partial[b * HID + t] = sred[0][t] + sred[1][t] + sred[2][t] + sred[3][t];
}

__global__ __launch_bounds__(256) void k2_m1(
    const float* __restrict__ x,
    const float* __restrict__ Wp, const float* __restrict__ bp,
    const float* __restrict__ Wm1, const float* __restrict__ bm1,
    const float* __restrict__ partial, float* __restrict__ m1) {
  __shared__ float sgemb[HID];
  __shared__ float sc[512];
  __shared__ float sred[4][64];
  __shared__ float snva[4];
  const int t = threadIdx.x;

  // n_valid
  {
    float mv = 0.f;
    for (int i = t; i < NSCAN; i += 256) mv += (x[i] != 1.0f) ? 1.f : 0.f;
    for (int off = 32; off; off >>= 1) mv += __shfl_down(mv, off, 64);
    if ((t & 63) == 0) snva[t >> 6] = mv;
  }
  __syncthreads();
  // gemb
  if (t < HID) {
    float sum = 0.f;
#pragma unroll
    for (int bb = 0; bb < NB1; ++bb) sum += partial[bb * HID + t];
    const float nv = snva[0] + snva[1] + snva[2] + snva[3];
    sgemb[t] = sum / nv;
  }
  __syncthreads();
  // c = gemb @ Wp + bp  (512 cols over 256 threads)
  for (int j = t; j < 512; j += 256) {
    float acc = bp[j];
#pragma unroll 16
    for (int k = 0; k < HID; ++k) acc = fmaf(sgemb[k], Wp[k * 512 + j], acc);
    sc[j] = acc;
  }
  __syncthreads();
  // m1 slice: 64 cols per block
  {
    const int jl = t & 63, g = t >> 6;
    const int j = blockIdx.x * 64 + jl;
    float acc = 0.f;
    const int k0 = g * 128;
#pragma unroll 8
    for (int ki = 0; ki < 128; ++ki)
      acc = fmaf(sc[k0 + ki], Wm1[(k0 + ki) * 1024 + j], acc);
    sred[g][jl] = acc;
  }
  __syncthreads();
  if (t < 64) {
    const int jj = blockIdx.x * 64 + t;
    const float v = sred[0][t] + sred[1][t] + sred[2][t] + sred[3][t] + bm1[jj];
    m1[jj] = fmaxf(v, 0.f);
  }
}

__global__ __launch_bounds__(256) void k3_out(
    const float* __restrict__ m1, const float* __restrict__ Wm2,
    const float* __restrict__ bm2, float* __restrict__ out) {
  __shared__ float sws[4];
  const int t = threadIdx.x;
  const int j = blockIdx.x;   // 0..199
  float acc = 0.f;
#pragma unroll
  for (int it = 0; it < 4; ++it) {
    const int k = t + it * 256;
    acc = fmaf(m1[k], Wm2[k * 200 + j], acc);
  }
  for (int off = 32; off; off >>= 1) acc += __shfl_down(acc, off, 64);
  if ((t & 63) == 0) sws[t >> 6] = acc;
  __syncthreads();
  if (t == 0) out[j] = sws[0] + sws[1] + sws[2] + sws[3] + bm2[j];
}

extern "C" void kernel_launch(void* const* d_in, const int* in_sizes, int n_in,
                              void* d_out, int out_size, void* d_ws,
                              size_t ws_size, hipStream_t stream) {
  const float* x   = (const float*)d_in[0];
  const float* W1  = (const float*)d_in[1];
  const float* b1  = (const float*)d_in[2];
  const float* W2  = (const float*)d_in[3];
  const float* b2  = (const float*)d_in[4];
  const float* W3  = (const float*)d_in[5];
  const float* b3  = (const float*)d_in[6];
  const float* Wp  = (const float*)d_in[7];
  const float* bp  = (const float*)d_in[8];
  const float* Wm1 = (const float*)d_in[9];
  const float* bm1 = (const float*)d_in[10];
  const float* Wm2 = (const float*)d_in[11];
  const float* bm2 = (const float*)d_in[12];

  float* ws = (float*)d_ws;
  float* partial = ws + WSF_PARTIAL;
  float* m1      = ws + WSF_M1;
  float* out     = (float*)d_out;

  k1_gcn<<<NB1, 256, 0, stream>>>(x, W1, b1, W2, b2, W3, b3, partial);
  k2_m1<<<16, 256, 0, stream>>>(x, Wp, bp, Wm1, bm1, partial, m1);
  k3_out<<<200, 256, 0, stream>>>(m1, Wm2, bm2, out);
}

// Round 4
// 19.535 us; speedup vs baseline: 2.0643x; 1.1541x over previous
//
#include <hip/hip_runtime.h>
#include <math.h>

// Graph2GraphModel: lidar-chain GCN (3 layers, HID=64) -> masked mean pool
// -> Wp(64x512) -> relu(Wm1 512x1024) -> Wm2(1024x200).
// 3 kernels. Round-3 lesson: k2 with 16 blocks was HBM-latency-bound on the
// cold 2MB Wm1 read (~10us). Fix: 64 blocks x 16 cols, float4 loads, shuffle
// reduce. k1 prep restricted to the 14-entry halo window.

#define NSCAN 360
#define HID 64
#define NB1 60      // k1 blocks
#define CHUNK 6     // nodes per k1 block
#define EXT 12      // CHUNK + 6 halo
#define NB2 64      // k2 blocks (16 m1 cols each)

// ws float-offset layout
#define WSF_PARTIAL 0                    // NB1*HID floats
#define WSF_M1      (NB1 * HID)          // 1024 floats

__device__ __forceinline__ void matmul64(int t, int glo, int ghi, int base,
                                         const float (*sh)[HID],
                                         float (*shw)[HID],
                                         const float (*sW)[HID]) {
  const int cnt = ghi - glo;
  const int off = glo - base;
  if (t < cnt * 16) {
    const int nl = off + (t >> 4);
    const int j4 = (t & 15) << 2;
    float a0 = 0.f, a1 = 0.f, a2 = 0.f, a3 = 0.f;
#pragma unroll 16
    for (int k = 0; k < HID; ++k) {
      const float hv = sh[nl][k];
      const float4 w = *reinterpret_cast<const float4*>(&sW[k][j4]);
      a0 = fmaf(hv, w.x, a0);
      a1 = fmaf(hv, w.y, a1);
      a2 = fmaf(hv, w.z, a2);
      a3 = fmaf(hv, w.w, a3);
    }
    float4 r; r.x = a0; r.y = a1; r.z = a2; r.w = a3;
    *reinterpret_cast<float4*>(&shw[nl][j4]) = r;
  }
}

// local-window aggregate: out nodes [olo,ohi), arrays indexed by (n-base),
// lmask[l] = mask(base-1+l), lcoef[l] = coef(base+l), linv[l] = inv(base+l)
__device__ __forceinline__ void agg_relu(int t, int olo, int ohi, int base,
                                         const float (*shw)[HID],
                                         float (*sh)[HID],
                                         const float* linv,
                                         const float* lcoef,
                                         const float* __restrict__ bias) {
  const int cnt = ohi - olo;
  for (int o = t; o < cnt * HID; o += 256) {
    const int nl = (o >> 6) + (olo - base), j = o & 63;
    const int n = base + nl;
    float v = linv[nl] * linv[nl] * shw[nl][j];
    if (n > 0)         v += lcoef[nl - 1] * shw[nl - 1][j];
    if (n < NSCAN - 1) v += lcoef[nl]     * shw[nl + 1][j];
    v += bias[j];
    sh[nl][j] = fmaxf(v, 0.f);
  }
}

__global__ __launch_bounds__(256) void k1_gcn(
    const float* __restrict__ x,
    const float* __restrict__ W1, const float* __restrict__ b1,
    const float* __restrict__ W2, const float* __restrict__ b2,
    const float* __restrict__ W3, const float* __restrict__ b3,
    float* __restrict__ partial) {
  __shared__ float lmask[EXT + 2];
  __shared__ float linv[EXT];
  __shared__ float lcoef[EXT];
  __shared__ float snod[EXT][2];
  __shared__ float sh[EXT][HID];
  __shared__ float shw[EXT][HID];
  __shared__ float sW[HID][HID];
  __shared__ float sred[4][HID];

  const int t = threadIdx.x;
  const int b = blockIdx.x;

  const int s = b * CHUNK, e = s + CHUNK;
  const int lo3 = max(0, s - 3), hi3 = min(NSCAN, e + 3);
  const int lo2 = max(0, s - 2), hi2 = min(NSCAN, e + 2);
  const int lo1 = max(0, s - 1), hi1 = min(NSCAN, e + 1);
  const int base = lo3;

  // ---- P0: mask window (wave0), trig nodes (wave1), W2 stage (waves2-3) ----
  if (t < EXT + 2) {
    const int gi = base - 1 + t;
    lmask[t] = (gi >= 0 && gi < NSCAN && x[gi] != 1.0f) ? 1.f : 0.f;
  } else if (t >= 64 && t < 64 + EXT) {
    const int l = t - 64, gi = base + l;
    if (gi < hi3) {
      const float lv = x[gi];
      const double a = (double)gi * (6.283185307179586476925287 / 359.0);
      snod[l][0] = lv * (float)cos(a);
      snod[l][1] = lv * (float)sin(a);
    }
  }
  if (t >= 128) {
    const float4* src = reinterpret_cast<const float4*>(W2);
    float4* dst = reinterpret_cast<float4*>(&sW[0][0]);
    for (int i = t - 128; i < 1024; i += 128) dst[i] = src[i];
  }
  __syncthreads();

  // ---- P1: inv -> coef (in-wave, wave0) ; layer-1 matmul (waves 1-3) ----
  if (t < 64) {
    if (t < EXT && base + t < hi3) {
      const float m = lmask[t + 1];
      const float deg = m * (1.f + lmask[t] + lmask[t + 2]);
      linv[t] = (deg > 0.f) ? 1.0f / sqrtf(deg) : 0.f;
    }
    __builtin_amdgcn_wave_barrier();
    if (t < EXT - 1 && base + t < min(NSCAN - 1, hi3 - 1)) {
      const float pair = lmask[t + 1] * lmask[t + 2];
      lcoef[t] = pair * linv[t] * linv[t + 1];
    }
  } else {
    for (int o = t - 64; o < (hi3 - lo3) * HID; o += 192) {
      const int nl = o >> 6, j = o & 63;
      shw[nl][j] = fmaf(snod[nl][0], W1[j], snod[nl][1] * W1[HID + j]);
    }
  }
  __syncthreads();

  agg_relu(t, lo2, hi2, base, shw, sh, linv, lcoef, b1);
  __syncthreads();
  matmul64(t, lo2, hi2, base, sh, shw, sW);
  __syncthreads();
  agg_relu(t, lo1, hi1, base, shw, sh, linv, lcoef, b2);
  {
    const float4* src = reinterpret_cast<const float4*>(W3);
    float4* dst = reinterpret_cast<float4*>(&sW[0][0]);
    for (int i = t; i < 1024; i += 256) dst[i] = src[i];
  }
  __syncthreads();
  matmul64(t, lo1, hi1, base, sh, shw, sW);
  __syncthreads();
  agg_relu(t, s, e, base, shw, sh, linv, lcoef, b3);
  __syncthreads();

  // ---- masked pool over own chunk ----
  {
    const int jl = t & 63, g = t >> 6;
    float acc = 0.f;
    for (int n = s + g; n < e; n += 4)
      acc += sh[n - base][jl] * lmask[n - base + 1];
    sred[g][jl] = acc;
  }
  __syncthreads();
  if (t < HID)
    partial[b * HID + t] = sred[0][t] + sred[1][t] + sred[2][t] + sred[3][t];
}

__global__ __launch_bounds__(256) void k2_m1(
    const float* __restrict__ x,
    const float* __restrict__ Wp, const float* __restrict__ bp,
    const float* __restrict__ Wm1, const float* __restrict__ bm1,
    const float* __restrict__ partial, float* __restrict__ m1) {
  __shared__ float sgemb[HID];
  __shared__ float sc[512];
  __shared__ float snva[4];
  __shared__ float4 swred[4][4];
  const int t = threadIdx.x;
  const int b = blockIdx.x;

  // n_valid (redundant per block)
  {
    float mv = 0.f;
    for (int i = t; i < NSCAN; i += 256) mv += (x[i] != 1.0f) ? 1.f : 0.f;
    for (int off = 32; off; off >>= 1) mv += __shfl_down(mv, off, 64);
    if ((t & 63) == 0) snva[t >> 6] = mv;
  }
  __syncthreads();
  // gemb
  if (t < HID) {
    float sum = 0.f;
#pragma unroll
    for (int bb = 0; bb < NB1; ++bb) sum += partial[bb * HID + t];
    const float nv = snva[0] + snva[1] + snva[2] + snva[3];
    sgemb[t] = sum / nv;
  }
  __syncthreads();
  // c = gemb @ Wp + bp (redundant per block)
  for (int j = t; j < 512; j += 256) {
    float acc = bp[j];
#pragma unroll 16
    for (int k = 0; k < HID; ++k) acc = fmaf(sgemb[k], Wp[k * 512 + j], acc);
    sc[j] = acc;
  }
  __syncthreads();
  // m1: 16 cols per block, float4 loads, 8-deep k-unroll
  {
    const int c4 = t & 3;          // float4 column chunk within block
    const int g  = t >> 2;         // 64 k-groups of 8
    const float4* wv = reinterpret_cast<const float4*>(Wm1) + b * 4 + c4;
    float4 a4; a4.x = 0.f; a4.y = 0.f; a4.z = 0.f; a4.w = 0.f;
    const int k0 = g * 8;
#pragma unroll 8
    for (int ki = 0; ki < 8; ++ki) {
      const float cv = sc[k0 + ki];
      const float4 w = wv[(k0 + ki) * 256];
      a4.x = fmaf(cv, w.x, a4.x);
      a4.y = fmaf(cv, w.y, a4.y);
      a4.z = fmaf(cv, w.z, a4.z);
      a4.w = fmaf(cv, w.w, a4.w);
    }
#pragma unroll
    for (int off = 4; off < 64; off <<= 1) {
      a4.x += __shfl_down(a4.x, off, 64);
      a4.y += __shfl_down(a4.y, off, 64);
      a4.z += __shfl_down(a4.z, off, 64);
      a4.w += __shfl_down(a4.w, off, 64);
    }
    if ((t & 63) < 4) swred[t >> 6][t & 63] = a4;
  }
  __syncthreads();
  if (t < 4) {
    float4 v = swred[0][t];
    const float4 v1 = swred[1][t], v2 = swred[2][t], v3 = swred[3][t];
    v.x += v1.x + v2.x + v3.x;
    v.y += v1.y + v2.y + v3.y;
    v.z += v1.z + v2.z + v3.z;
    v.w += v1.w + v2.w + v3.w;
    const float4 bb = reinterpret_cast<const float4*>(bm1)[b * 4 + t];
    float4 r;
    r.x = fmaxf(v.x + bb.x, 0.f);
    r.y = fmaxf(v.y + bb.y, 0.f);
    r.z = fmaxf(v.z + bb.z, 0.f);
    r.w = fmaxf(v.w + bb.w, 0.f);
    reinterpret_cast<float4*>(m1)[b * 4 + t] = r;
  }
}

__global__ __launch_bounds__(256) void k3_out(
    const float* __restrict__ m1, const float* __restrict__ Wm2,
    const float* __restrict__ bm2, float* __restrict__ out) {
  __shared__ float sws[4];
  const int t = threadIdx.x;
  const int j = blockIdx.x;   // 0..199
  float acc = 0.f;
#pragma unroll
  for (int it = 0; it < 4; ++it) {
    const int k = t + it * 256;
    acc = fmaf(m1[k], Wm2[k * 200 + j], acc);
  }
  for (int off = 32; off; off >>= 1) acc += __shfl_down(acc, off, 64);
  if ((t & 63) == 0) sws[t >> 6] = acc;
  __syncthreads();
  if (t == 0) out[j] = sws[0] + sws[1] + sws[2] + sws[3] + bm2[j];
}

extern "C" void kernel_launch(void* const* d_in, const int* in_sizes, int n_in,
                              void* d_out, int out_size, void* d_ws,
                              size_t ws_size, hipStream_t stream) {
  const float* x   = (const float*)d_in[0];
  const float* W1  = (const float*)d_in[1];
  const float* b1  = (const float*)d_in[2];
  const float* W2  = (const float*)d_in[3];
  const float* b2  = (const float*)d_in[4];
  const float* W3  = (const float*)d_in[5];
  const float* b3  = (const float*)d_in[6];
  const float* Wp  = (const float*)d_in[7];
  const float* bp  = (const float*)d_in[8];
  const float* Wm1 = (const float*)d_in[9];
  const float* bm1 = (const float*)d_in[10];
  const float* Wm2 = (const float*)d_in[11];
  const float* bm2 = (const float*)d_in[12];

  float* ws = (float*)d_ws;
  float* partial = ws + WSF_PARTIAL;
  float* m1      = ws + WSF_M1;
  float* out     = (float*)d_out;

  k1_gcn<<<NB1, 256, 0, stream>>>(x, W1, b1, W2, b2, W3, b3, partial);
  k2_m1<<<NB2, 256, 0, stream>>>(x, Wp, bp, Wm1, bm1, partial, m1);
  k3_out<<<200, 256, 0, stream>>>(m1, Wm2, bm2, out);
}

// Round 5
// 18.246 us; speedup vs baseline: 2.2102x; 1.0707x over previous
//
#include <hip/hip_runtime.h>
#include <math.h>

// Graph2GraphModel: lidar-chain GCN (3 layers, HID=64) -> masked mean pool
// -> Wp(64x512) -> relu(Wm1 512x1024) -> Wm2(1024x200).
//
// 2 kernels (round-4 lesson: per-graph-node overhead ~4-5us dominates; fold
// the final linear layer into k2 via fp32 atomicAdd):
//  k1 (60 blocks): GCN halo chunks -> partial pool sums; block 0 also
//     initializes out = bm2 (graph-ordered before k2 => replay-safe).
//  k2 (64 blocks): gemb + c (redundant per block) + 16-col slice of m1 +
//     atomicAdd of (m1_slice @ Wm2_rows) into out (coalesced row reads).

#define NSCAN 360
#define HID 64
#define NB1 60      // k1 blocks
#define CHUNK 6     // nodes per k1 block
#define EXT 12      // CHUNK + 6 halo
#define NB2 64      // k2 blocks (16 m1 cols each)

#define WSF_PARTIAL 0                    // NB1*HID floats

__device__ __forceinline__ void matmul64(int t, int glo, int ghi, int base,
                                         const float (*sh)[HID],
                                         float (*shw)[HID],
                                         const float (*sW)[HID]) {
  const int cnt = ghi - glo;
  const int off = glo - base;
  if (t < cnt * 16) {
    const int nl = off + (t >> 4);
    const int j4 = (t & 15) << 2;
    float a0 = 0.f, a1 = 0.f, a2 = 0.f, a3 = 0.f;
#pragma unroll 16
    for (int k = 0; k < HID; ++k) {
      const float hv = sh[nl][k];
      const float4 w = *reinterpret_cast<const float4*>(&sW[k][j4]);
      a0 = fmaf(hv, w.x, a0);
      a1 = fmaf(hv, w.y, a1);
      a2 = fmaf(hv, w.z, a2);
      a3 = fmaf(hv, w.w, a3);
    }
    float4 r; r.x = a0; r.y = a1; r.z = a2; r.w = a3;
    *reinterpret_cast<float4*>(&shw[nl][j4]) = r;
  }
}

// local-window aggregate: arrays indexed by (n-base);
// lmask[l]=mask(base-1+l), linv[l]=inv(base+l), lcoef[l]=coef(base+l)
__device__ __forceinline__ void agg_relu(int t, int olo, int ohi, int base,
                                         const float (*shw)[HID],
                                         float (*sh)[HID],
                                         const float* linv,
                                         const float* lcoef,
                                         const float* __restrict__ bias) {
  const int cnt = ohi - olo;
  for (int o = t; o < cnt * HID; o += 256) {
    const int nl = (o >> 6) + (olo - base), j = o & 63;
    const int n = base + nl;
    float v = linv[nl] * linv[nl] * shw[nl][j];
    if (n > 0)         v += lcoef[nl - 1] * shw[nl - 1][j];
    if (n < NSCAN - 1) v += lcoef[nl]     * shw[nl + 1][j];
    v += bias[j];
    sh[nl][j] = fmaxf(v, 0.f);
  }
}

__global__ __launch_bounds__(256) void k1_gcn(
    const float* __restrict__ x,
    const float* __restrict__ W1, const float* __restrict__ b1,
    const float* __restrict__ W2, const float* __restrict__ b2,
    const float* __restrict__ W3, const float* __restrict__ b3,
    const float* __restrict__ bm2,
    float* __restrict__ partial, float* __restrict__ out) {
  __shared__ float lmask[EXT + 2];
  __shared__ float linv[EXT];
  __shared__ float lcoef[EXT];
  __shared__ float snod[EXT][2];
  __shared__ float sh[EXT][HID];
  __shared__ float shw[EXT][HID];
  __shared__ float sW[HID][HID];
  __shared__ float sred[4][HID];

  const int t = threadIdx.x;
  const int b = blockIdx.x;

  // out = bm2 each call (block 0 only; k2 atomicAdds on top, graph-ordered)
  if (b == 0 && t < 200) out[t] = bm2[t];

  const int s = b * CHUNK, e = s + CHUNK;
  const int lo3 = max(0, s - 3), hi3 = min(NSCAN, e + 3);
  const int lo2 = max(0, s - 2), hi2 = min(NSCAN, e + 2);
  const int lo1 = max(0, s - 1), hi1 = min(NSCAN, e + 1);
  const int base = lo3;

  // ---- P0: mask window (wave0), trig nodes (wave1), W2 stage (waves2-3) ----
  if (t < EXT + 2) {
    const int gi = base - 1 + t;
    lmask[t] = (gi >= 0 && gi < NSCAN && x[gi] != 1.0f) ? 1.f : 0.f;
  } else if (t >= 64 && t < 64 + EXT) {
    const int l = t - 64, gi = base + l;
    if (gi < hi3) {
      const float lv = x[gi];
      const double a = (double)gi * (6.283185307179586476925287 / 359.0);
      snod[l][0] = lv * (float)cos(a);
      snod[l][1] = lv * (float)sin(a);
    }
  }
  if (t >= 128) {
    const float4* src = reinterpret_cast<const float4*>(W2);
    float4* dst = reinterpret_cast<float4*>(&sW[0][0]);
    for (int i = t - 128; i < 1024; i += 128) dst[i] = src[i];
  }
  __syncthreads();

  // ---- P1: inv -> coef (wave0) ; layer-1 matmul (waves 1-3) ----
  if (t < 64) {
    if (t < EXT && base + t < hi3) {
      const float m = lmask[t + 1];
      const float deg = m * (1.f + lmask[t] + lmask[t + 2]);
      linv[t] = (deg > 0.f) ? 1.0f / sqrtf(deg) : 0.f;
    }
    __builtin_amdgcn_wave_barrier();
    if (t < EXT - 1 && base + t < min(NSCAN - 1, hi3 - 1)) {
      const float pair = lmask[t + 1] * lmask[t + 2];
      lcoef[t] = pair * linv[t] * linv[t + 1];
    }
  } else {
    for (int o = t - 64; o < (hi3 - lo3) * HID; o += 192) {
      const int nl = o >> 6, j = o & 63;
      shw[nl][j] = fmaf(snod[nl][0], W1[j], snod[nl][1] * W1[HID + j]);
    }
  }
  __syncthreads();

  agg_relu(t, lo2, hi2, base, shw, sh, linv, lcoef, b1);
  __syncthreads();
  matmul64(t, lo2, hi2, base, sh, shw, sW);
  __syncthreads();
  agg_relu(t, lo1, hi1, base, shw, sh, linv, lcoef, b2);
  {
    const float4* src = reinterpret_cast<const float4*>(W3);
    float4* dst = reinterpret_cast<float4*>(&sW[0][0]);
    for (int i = t; i < 1024; i += 256) dst[i] = src[i];
  }
  __syncthreads();
  matmul64(t, lo1, hi1, base, sh, shw, sW);
  __syncthreads();
  agg_relu(t, s, e, base, shw, sh, linv, lcoef, b3);
  __syncthreads();

  // ---- masked pool over own chunk ----
  {
    const int jl = t & 63, g = t >> 6;
    float acc = 0.f;
    for (int n = s + g; n < e; n += 4)
      acc += sh[n - base][jl] * lmask[n - base + 1];
    sred[g][jl] = acc;
  }
  __syncthreads();
  if (t < HID)
    partial[b * HID + t] = sred[0][t] + sred[1][t] + sred[2][t] + sred[3][t];
}

__global__ __launch_bounds__(256) void k2_mlp(
    const float* __restrict__ x,
    const float* __restrict__ Wp, const float* __restrict__ bp,
    const float* __restrict__ Wm1, const float* __restrict__ bm1,
    const float* __restrict__ Wm2,
    const float* __restrict__ partial, float* __restrict__ out) {
  __shared__ float sgemb[HID];
  __shared__ float sc[512];
  __shared__ float snva[4];
  __shared__ float4 swred[4][4];
  __shared__ float sm1[16];
  const int t = threadIdx.x;
  const int b = blockIdx.x;

  // n_valid (redundant per block)
  {
    float mv = 0.f;
    for (int i = t; i < NSCAN; i += 256) mv += (x[i] != 1.0f) ? 1.f : 0.f;
    for (int off = 32; off; off >>= 1) mv += __shfl_down(mv, off, 64);
    if ((t & 63) == 0) snva[t >> 6] = mv;
  }
  __syncthreads();
  // gemb
  if (t < HID) {
    float sum = 0.f;
#pragma unroll
    for (int bb = 0; bb < NB1; ++bb) sum += partial[bb * HID + t];
    const float nv = snva[0] + snva[1] + snva[2] + snva[3];
    sgemb[t] = sum / nv;
  }
  __syncthreads();
  // c = gemb @ Wp + bp (redundant per block)
  for (int j = t; j < 512; j += 256) {
    float acc = bp[j];
#pragma unroll 16
    for (int k = 0; k < HID; ++k) acc = fmaf(sgemb[k], Wp[k * 512 + j], acc);
    sc[j] = acc;
  }
  __syncthreads();
  // m1 slice: 16 cols per block, float4 loads, 8-deep k-unroll
  {
    const int c4 = t & 3;          // which float4 col-chunk of the 16 cols
    const int g  = t >> 2;         // 64 k-groups of 8
    const float4* wv = reinterpret_cast<const float4*>(Wm1) + b * 4 + c4;
    float4 a4; a4.x = 0.f; a4.y = 0.f; a4.z = 0.f; a4.w = 0.f;
    const int k0 = g * 8;
#pragma unroll 8
    for (int ki = 0; ki < 8; ++ki) {
      const float cv = sc[k0 + ki];
      const float4 w = wv[(k0 + ki) * 256];
      a4.x = fmaf(cv, w.x, a4.x);
      a4.y = fmaf(cv, w.y, a4.y);
      a4.z = fmaf(cv, w.z, a4.z);
      a4.w = fmaf(cv, w.w, a4.w);
    }
#pragma unroll
    for (int off = 4; off < 64; off <<= 1) {
      a4.x += __shfl_down(a4.x, off, 64);
      a4.y += __shfl_down(a4.y, off, 64);
      a4.z += __shfl_down(a4.z, off, 64);
      a4.w += __shfl_down(a4.w, off, 64);
    }
    if ((t & 63) < 4) swred[t >> 6][t & 63] = a4;
  }
  __syncthreads();
  if (t < 4) {
    float4 v = swred[0][t];
    const float4 v1 = swred[1][t], v2 = swred[2][t], v3 = swred[3][t];
    v.x += v1.x + v2.x + v3.x;
    v.y += v1.y + v2.y + v3.y;
    v.z += v1.z + v2.z + v3.z;
    v.w += v1.w + v2.w + v3.w;
    const float4 bb = reinterpret_cast<const float4*>(bm1)[b * 4 + t];
    float4 r;
    r.x = fmaxf(v.x + bb.x, 0.f);
    r.y = fmaxf(v.y + bb.y, 0.f);
    r.z = fmaxf(v.z + bb.z, 0.f);
    r.w = fmaxf(v.w + bb.w, 0.f);
    reinterpret_cast<float4*>(sm1)[t] = r;
  }
  __syncthreads();
  // out contribution: rows j0..j0+15 of Wm2, coalesced; atomicAdd into out
  if (t < 200) {
    const int j0 = b * 16;
    float acc = 0.f;
#pragma unroll 16
    for (int r = 0; r < 16; ++r)
      acc = fmaf(sm1[r], Wm2[(j0 + r) * 200 + t], acc);
    atomicAdd(&out[t], acc);
  }
}

extern "C" void kernel_launch(void* const* d_in, const int* in_sizes, int n_in,
                              void* d_out, int out_size, void* d_ws,
                              size_t ws_size, hipStream_t stream) {
  const float* x   = (const float*)d_in[0];
  const float* W1  = (const float*)d_in[1];
  const float* b1  = (const float*)d_in[2];
  const float* W2  = (const float*)d_in[3];
  const float* b2  = (const float*)d_in[4];
  const float* W3  = (const float*)d_in[5];
  const float* b3  = (const float*)d_in[6];
  const float* Wp  = (const float*)d_in[7];
  const float* bp  = (const float*)d_in[8];
  const float* Wm1 = (const float*)d_in[9];
  const float* bm1 = (const float*)d_in[10];
  const float* Wm2 = (const float*)d_in[11];
  const float* bm2 = (const float*)d_in[12];

  float* ws = (float*)d_ws;
  float* partial = ws + WSF_PARTIAL;
  float* out     = (float*)d_out;

  k1_gcn<<<NB1, 256, 0, stream>>>(x, W1, b1, W2, b2, W3, b3, bm2, partial, out);
  k2_mlp<<<NB2, 256, 0, stream>>>(x, Wp, bp, Wm1, bm1, Wm2, partial, out);
}